// Round 7
// baseline (90.372 us; speedup 1.0000x reference)
//
#include <hip/hip_runtime.h>

constexpr int D = 20;

typedef float f4 __attribute__((ext_vector_type(4)));
typedef unsigned int u32;

__device__ __forceinline__ u32 bf16_rne(float f) {
    u32 u = __float_as_uint(f);
    return (u + 0x7FFFu + ((u >> 16) & 1u)) >> 16;
}

// Pass 1: pack (qz_w, qz_b) as bf16 pair into ONE uint32 per entry.
// Table shrinks 16 MB -> 8.4 MB; each row's gather becomes one 4B load.
__global__ __launch_bounds__(256) void cevae_build_tab(
    const f4* __restrict__ qw, const f4* __restrict__ qb,
    uint4* __restrict__ tab, int nq)   // nq = nc/4
{
    int i = blockIdx.x * 256 + threadIdx.x;
    if (i >= nq) return;
    f4 w = qw[i];
    f4 b = qb[i];
    uint4 o;
    o.x = (bf16_rne(w.x) << 16) | bf16_rne(b.x);
    o.y = (bf16_rne(w.y) << 16) | bf16_rne(b.y);
    o.z = (bf16_rne(w.z) << 16) | bf16_rne(b.z);
    o.w = (bf16_rne(w.w) << 16) | bf16_rne(b.w);
    tab[i] = o;
}

// Pass 2: uniform fused kernel, 4 rows per thread.
//  - 4 independent 4B gathers issued early (hidden under 40 fill stores)
//  - head outputs stored as float4 (4 rows at once)
//  - per-thread x_logits span: 2 regions x 320B contiguous, full-line coverage
template <bool USE_TAB>
__global__ __launch_bounds__(256) void cevae_r4_kernel(
    const f4* __restrict__ x4, const f4* __restrict__ t4,
    const f4* __restrict__ y4, const u32* __restrict__ tab,
    const float* __restrict__ qz_w, const float* __restrict__ qz_b,
    const float* __restrict__ dx_w, const float* __restrict__ dx_b,
    const float* __restrict__ sc_tw, const float* __restrict__ sc_tb,
    const float* __restrict__ sc_y0w, const float* __restrict__ sc_y0b,
    const float* __restrict__ sc_y1w, const float* __restrict__ sc_y1b,
    const float* __restrict__ pz, float* __restrict__ out, int n_rows)
{
    int m = blockIdx.x * 256 + threadIdx.x;     // row-group index (4 rows)
    int ng = n_rows >> 2;
    if (m >= ng) return;

    f4 tv = t4[m];
    f4 yv = y4[m];

    // ---- compute the 4 combo indices (row-by-row to bound VGPR pressure) ----
    const f4* xr = x4 + (size_t)m * 20;
    u32 idx[4];
#pragma unroll
    for (int r = 0; r < 4; ++r) {
        float tr = (r == 0) ? tv.x : (r == 1) ? tv.y : (r == 2) ? tv.z : tv.w;
        u32 id = (tr != 0.0f) ? (1u << 20) : 0u;
#pragma unroll
        for (int k = 0; k < 5; ++k) {
            f4 v = xr[5 * r + k];
            int sh = 19 - 4 * k;
            id |= ((u32)v.x) << sh;
            id |= ((u32)v.y) << (sh - 1);
            id |= ((u32)v.z) << (sh - 2);
            id |= ((u32)v.w) << (sh - 3);
        }
        idx[r] = id;
    }

    // ---- issue 4 independent random gathers (stay in flight during fill) ----
    u32 g0, g1, g2, g3;
    float w0f, b0f, w1f, b1f, w2f, b2f, w3f, b3f;
    if (USE_TAB) {
        g0 = tab[idx[0]]; g1 = tab[idx[1]]; g2 = tab[idx[2]]; g3 = tab[idx[3]];
    } else {
        w0f = qz_w[idx[0]]; b0f = qz_b[idx[0]];
        w1f = qz_w[idx[1]]; b1f = qz_b[idx[1]];
        w2f = qz_w[idx[2]]; b2f = qz_b[idx[2]];
        w3f = qz_w[idx[3]]; b3f = qz_b[idx[3]];
    }

    // ---- fill x_logits0/1 for own 4 rows (independent of gathers) ----
    f4 p0[5], p1[5];
#pragma unroll
    for (int k = 0; k < 5; ++k) {
        float b0 = dx_b[4 * k + 0], b1 = dx_b[4 * k + 1];
        float b2 = dx_b[4 * k + 2], b3 = dx_b[4 * k + 3];
        float w0 = dx_w[4 * k + 0], w1 = dx_w[4 * k + 1];
        float w2 = dx_w[4 * k + 2], w3 = dx_w[4 * k + 3];
        p0[k] = f4{b0, b1, b2, b3};
        p1[k] = f4{w0 + b0, w1 + b1, w2 + b2, w3 + b3};
    }
    f4* r0 = (f4*)(out + (size_t)n_rows) + (size_t)m * 20;            // x_logits0
    f4* r1 = (f4*)(out + (size_t)(1 + D) * n_rows) + (size_t)m * 20;  // x_logits1
#pragma unroll
    for (int k = 0; k < 20; ++k) r0[k] = p0[k % 5];
#pragma unroll
    for (int k = 0; k < 20; ++k) r1[k] = p1[k % 5];

    // ---- scalar heads (float4 per 4 rows) ----
    float tw  = *sc_tw,  tb  = *sc_tb;
    float y0w = *sc_y0w, y0b = *sc_y0b;
    float y1w = *sc_y1w, y1b = *sc_y1b;

    size_t o3 = (size_t)n_rows * (size_t)(1 + 2 * D);
    ((f4*)(out + o3))[m] = f4{tb, tb, tb, tb};
    float t1v = tw + tb;
    ((f4*)(out + o3 + (size_t)n_rows))[m] = f4{t1v, t1v, t1v, t1v};
    float dy0 = y1b - y0b;
    float dy1 = (y1w + y1b) - (y0w + y0b), c1 = y0w + y0b;
    ((f4*)(out + o3 + 2 * (size_t)n_rows))[m] =
        f4{fmaf(tv.x, dy0, y0b), fmaf(tv.y, dy0, y0b),
           fmaf(tv.z, dy0, y0b), fmaf(tv.w, dy0, y0b)};
    ((f4*)(out + o3 + 3 * (size_t)n_rows))[m] =
        f4{fmaf(tv.x, dy1, c1), fmaf(tv.y, dy1, c1),
           fmaf(tv.z, dy1, c1), fmaf(tv.w, dy1, c1)};
    if (m == 0) out[o3 + 4 * (size_t)n_rows] = pz[0];

    // ---- consume gathers -> z_logits (float4 store) ----
    f4 z;
    if (USE_TAB) {
        z.x = fmaf(__uint_as_float(g0 & 0xFFFF0000u), yv.x, __uint_as_float(g0 << 16));
        z.y = fmaf(__uint_as_float(g1 & 0xFFFF0000u), yv.y, __uint_as_float(g1 << 16));
        z.z = fmaf(__uint_as_float(g2 & 0xFFFF0000u), yv.z, __uint_as_float(g2 << 16));
        z.w = fmaf(__uint_as_float(g3 & 0xFFFF0000u), yv.w, __uint_as_float(g3 << 16));
    } else {
        z = f4{fmaf(w0f, yv.x, b0f), fmaf(w1f, yv.y, b1f),
               fmaf(w2f, yv.z, b2f), fmaf(w3f, yv.w, b3f)};
    }
    ((f4*)out)[m] = z;
}

extern "C" void kernel_launch(void* const* d_in, const int* in_sizes, int n_in,
                              void* d_out, int out_size, void* d_ws, size_t ws_size,
                              hipStream_t stream) {
    const float* x    = (const float*)d_in[0];
    const float* t    = (const float*)d_in[1];
    const float* y    = (const float*)d_in[2];
    const float* qz_w = (const float*)d_in[3];
    const float* qz_b = (const float*)d_in[4];
    const float* dx_w = (const float*)d_in[5];
    const float* dx_b = (const float*)d_in[6];
    const float* t_w  = (const float*)d_in[7];
    const float* t_b  = (const float*)d_in[8];
    const float* y0_w = (const float*)d_in[9];
    const float* y0_b = (const float*)d_in[10];
    const float* y1_w = (const float*)d_in[11];
    const float* y1_b = (const float*)d_in[12];
    const float* pz   = (const float*)d_in[13];
    float* out = (float*)d_out;

    int n_rows = in_sizes[0] / D;            // 1,000,000
    int nc     = in_sizes[3];                // 2^21
    int ng     = n_rows / 4;                 // 250,000 row-groups
    int blocks = (ng + 255) / 256;           // 977

    size_t tab_bytes = (size_t)nc * sizeof(u32);   // 8.4 MB
    if (ws_size >= tab_bytes) {
        uint4* tab = (uint4*)d_ws;
        int nq = nc / 4;                     // 524,288
        cevae_build_tab<<<(nq + 255) / 256, 256, 0, stream>>>(
            (const f4*)qz_w, (const f4*)qz_b, tab, nq);
        cevae_r4_kernel<true><<<blocks, 256, 0, stream>>>(
            (const f4*)x, (const f4*)t, (const f4*)y, (const u32*)tab,
            qz_w, qz_b, dx_w, dx_b, t_w, t_b, y0_w, y0_b, y1_w, y1_b,
            pz, out, n_rows);
    } else {
        cevae_r4_kernel<false><<<blocks, 256, 0, stream>>>(
            (const f4*)x, (const f4*)t, (const f4*)y, nullptr,
            qz_w, qz_b, dx_w, dx_b, t_w, t_b, y0_w, y0_b, y1_w, y1_b,
            pz, out, n_rows);
    }
}

// Round 8
// 75.555 us; speedup vs baseline: 1.1961x; 1.1961x over previous
//
#include <hip/hip_runtime.h>

constexpr int D = 20;

typedef float f4 __attribute__((ext_vector_type(4)));
typedef unsigned int u32;

__device__ __forceinline__ u32 bf16_rne(float f) {
    u32 u = __float_as_uint(f);
    return (u + 0x7FFFu + ((u >> 16) & 1u)) >> 16;
}

// Pass 1: pack (qz_w, qz_b) as bf16 pair into ONE uint32 per entry.
// Table shrinks 16.8 MB -> 8.4 MB; each row's gather is one 4B load.
__global__ __launch_bounds__(256) void cevae_build_tab(
    const f4* __restrict__ qw, const f4* __restrict__ qb,
    uint4* __restrict__ tab, int nq)   // nq = nc/4
{
    int i = blockIdx.x * 256 + threadIdx.x;
    if (i >= nq) return;
    f4 w = qw[i];
    f4 b = qb[i];
    uint4 o;
    o.x = (bf16_rne(w.x) << 16) | bf16_rne(b.x);
    o.y = (bf16_rne(w.y) << 16) | bf16_rne(b.y);
    o.z = (bf16_rne(w.z) << 16) | bf16_rne(b.z);
    o.w = (bf16_rne(w.w) << 16) | bf16_rne(b.w);
    tab[i] = o;
}

// Pass 2: block-specialized fused kernel (round-6 structure). Roles in groups
// of 8 consecutive blocks so both roles round-robin evenly across 8 XCDs.
//   rows job: one 4B gather -> z; y_logits0/1 (needs t); 1 row/thread,
//             all stores lane-consecutive.
//   fill job: flat coalesced f4 fill of x_logits0/1 + constant t_logits0/1.
template <bool USE_TAB>
__global__ __launch_bounds__(256) void cevae_fused6_kernel(
    const float* __restrict__ x, const float* __restrict__ t,
    const float* __restrict__ y, const u32* __restrict__ tab,
    const float* __restrict__ qz_w, const float* __restrict__ qz_b,
    const float* __restrict__ dx_w, const float* __restrict__ dx_b,
    const float* __restrict__ sc_tw, const float* __restrict__ sc_tb,
    const float* __restrict__ sc_y0w, const float* __restrict__ sc_y0b,
    const float* __restrict__ sc_y1w, const float* __restrict__ sc_y1b,
    const float* __restrict__ pz, float* __restrict__ out, int n_rows,
    int n_job_blocks)
{
    int bid = blockIdx.x;
    int sub = ((bid >> 4) << 3) | (bid & 7);   // block index within its role
    size_t o3 = (size_t)n_rows * (size_t)(1 + 2 * D);

    if (((bid >> 3) & 1) == 0) {
        // ---------------- rows job ----------------
        int n = sub * 256 + threadIdx.x;
        if (n >= n_rows) return;

        const f4* xr = (const f4*)(x + (size_t)n * D);
        f4 a = xr[0];
        f4 b = xr[1];
        f4 c = xr[2];
        f4 d = xr[3];
        f4 e = xr[4];
        float tv = t[n];
        float yv = y[n];

        unsigned idx = (tv != 0.0f) ? (1u << 20) : 0u;
        idx |= ((unsigned)a.x) << 19;
        idx |= ((unsigned)a.y) << 18;
        idx |= ((unsigned)a.z) << 17;
        idx |= ((unsigned)a.w) << 16;
        idx |= ((unsigned)b.x) << 15;
        idx |= ((unsigned)b.y) << 14;
        idx |= ((unsigned)b.z) << 13;
        idx |= ((unsigned)b.w) << 12;
        idx |= ((unsigned)c.x) << 11;
        idx |= ((unsigned)c.y) << 10;
        idx |= ((unsigned)c.z) << 9;
        idx |= ((unsigned)c.w) << 8;
        idx |= ((unsigned)d.x) << 7;
        idx |= ((unsigned)d.y) << 6;
        idx |= ((unsigned)d.z) << 5;
        idx |= ((unsigned)d.w) << 4;
        idx |= ((unsigned)e.x) << 3;
        idx |= ((unsigned)e.y) << 2;
        idx |= ((unsigned)e.z) << 1;
        idx |= ((unsigned)e.w);

        float z;
        if (USE_TAB) {
            u32 g = tab[idx];                      // ONE random 4B request
            z = fmaf(__uint_as_float(g & 0xFFFF0000u), yv,
                     __uint_as_float(g << 16));
        } else {
            z = fmaf(qz_w[idx], yv, qz_b[idx]);
        }
        out[n] = z;

        float y0w = *sc_y0w, y0b = *sc_y0b;
        float y1w = *sc_y1w, y1b = *sc_y1b;

        // layout: [z(N)][xl0(N*D)][xl1(N*D)][t0(N)][t1(N)][y0(N)][y1(N)][pz(1)]
        out[o3 + 2 * (size_t)n_rows + n] = fmaf(tv, y1b - y0b, y0b);
        out[o3 + 3 * (size_t)n_rows + n] = fmaf(tv, (y1w + y1b) - (y0w + y0b), y0w + y0b);
        if (n == 0) out[o3 + 4 * (size_t)n_rows] = pz[0];
    } else {
        // ---------------- fill job (coalesced flat f4 stores) ----------------
        unsigned Q = (unsigned)n_rows * D / 4;      // f4 count per region (5M)
        f4* r0 = (f4*)(out + n_rows);               // x_logits0
        f4* r1 = r0 + Q;                            // x_logits1
        unsigned stride = (unsigned)n_job_blocks * 256;
        unsigned q0 = (unsigned)sub * 256 + threadIdx.x;
        for (unsigned q = q0; q < Q; q += stride) {
            int cb = (int)(q % 5u) * 4;             // column base 0,4,8,12,16
            float b0 = dx_b[cb + 0], b1 = dx_b[cb + 1];
            float b2 = dx_b[cb + 2], b3 = dx_b[cb + 3];
            float w0 = dx_w[cb + 0], w1 = dx_w[cb + 1];
            float w2 = dx_w[cb + 2], w3 = dx_w[cb + 3];
            f4 v0 = {b0, b1, b2, b3};
            f4 v1 = {w0 + b0, w1 + b1, w2 + b2, w3 + b3};
            r0[q] = v0;
            r1[q] = v1;
        }
        // constant heads: t_logits0 = tb, t_logits1 = tw + tb (pure splats)
        float tw = *sc_tw, tb = *sc_tb;
        f4 s0 = {tb, tb, tb, tb};
        float t1v = tw + tb;
        f4 s1 = {t1v, t1v, t1v, t1v};
        unsigned Qt = (unsigned)n_rows / 4;         // 250K f4 per region
        f4* h0 = (f4*)(out + o3);
        f4* h1 = (f4*)(out + o3 + (size_t)n_rows);
        for (unsigned q = q0; q < Qt; q += stride) {
            h0[q] = s0;
            h1[q] = s1;
        }
    }
}

extern "C" void kernel_launch(void* const* d_in, const int* in_sizes, int n_in,
                              void* d_out, int out_size, void* d_ws, size_t ws_size,
                              hipStream_t stream) {
    const float* x    = (const float*)d_in[0];
    const float* t    = (const float*)d_in[1];
    const float* y    = (const float*)d_in[2];
    const float* qz_w = (const float*)d_in[3];
    const float* qz_b = (const float*)d_in[4];
    const float* dx_w = (const float*)d_in[5];
    const float* dx_b = (const float*)d_in[6];
    const float* t_w  = (const float*)d_in[7];
    const float* t_b  = (const float*)d_in[8];
    const float* y0_w = (const float*)d_in[9];
    const float* y0_b = (const float*)d_in[10];
    const float* y1_w = (const float*)d_in[11];
    const float* y1_b = (const float*)d_in[12];
    const float* pz   = (const float*)d_in[13];
    float* out = (float*)d_out;

    int n_rows = in_sizes[0] / D;            // 1,000,000
    int nc     = in_sizes[3];                // 2^21
    int n_rb = (n_rows + 255) / 256;         // 3907 rows blocks needed
    int n_groups = (n_rb + 7) / 8;           // groups of 8 blocks per role
    int n_job_blocks = n_groups * 8;         // blocks per role

    size_t tab_bytes = (size_t)nc * sizeof(u32);   // 8.4 MB
    if (ws_size >= tab_bytes) {
        uint4* tab = (uint4*)d_ws;
        int nq = nc / 4;                     // 524,288
        cevae_build_tab<<<(nq + 255) / 256, 256, 0, stream>>>(
            (const f4*)qz_w, (const f4*)qz_b, tab, nq);
        cevae_fused6_kernel<true><<<n_groups * 16, 256, 0, stream>>>(
            x, t, y, (const u32*)tab, qz_w, qz_b, dx_w, dx_b, t_w, t_b,
            y0_w, y0_b, y1_w, y1_b, pz, out, n_rows, n_job_blocks);
    } else {
        cevae_fused6_kernel<false><<<n_groups * 16, 256, 0, stream>>>(
            x, t, y, nullptr, qz_w, qz_b, dx_w, dx_b, t_w, t_b,
            y0_w, y0_b, y1_w, y1_b, pz, out, n_rows, n_job_blocks);
    }
}

// Round 9
// 67.519 us; speedup vs baseline: 1.3385x; 1.1190x over previous
//
#include <hip/hip_runtime.h>

constexpr int D = 20;

typedef float f4 __attribute__((ext_vector_type(4)));
typedef unsigned int u32;

__device__ __forceinline__ u32 bf16_rne(float f) {
    u32 u = __float_as_uint(f);
    return (u + 0x7FFFu + ((u >> 16) & 1u)) >> 16;
}

// ---------------------------------------------------------------------------
// Kernel A: (a) build bf16-packed gather table (8.4 MB), (b) all pure-fill
// outputs: x_logits0/1 + constant t_logits0/1. Role by block range; both
// roles are multiples of 8 blocks -> even XCD spread. Working set ~193 MB
// (< 256 MB L3) so the freshly written table largely survives into kernel B.
// ---------------------------------------------------------------------------
__global__ __launch_bounds__(256) void cevae_A_build_fill(
    const f4* __restrict__ qw, const f4* __restrict__ qb,
    uint4* __restrict__ tab, int nq,              // nq = nc/4 u32x4 entries
    const float* __restrict__ dx_w, const float* __restrict__ dx_b,
    const float* __restrict__ sc_tw, const float* __restrict__ sc_tb,
    float* __restrict__ out, int n_rows,
    int n_build_blocks, int n_fill_blocks)
{
    int bid = blockIdx.x;
    if (bid < n_build_blocks) {
        // ---- table build: coalesced, 16.8 MB read + 8.4 MB write ----
        int i = bid * 256 + threadIdx.x;
        if (i >= nq) return;
        f4 w = qw[i];
        f4 b = qb[i];
        uint4 o;
        o.x = (bf16_rne(w.x) << 16) | bf16_rne(b.x);
        o.y = (bf16_rne(w.y) << 16) | bf16_rne(b.y);
        o.z = (bf16_rne(w.z) << 16) | bf16_rne(b.z);
        o.w = (bf16_rne(w.w) << 16) | bf16_rne(b.w);
        tab[i] = o;
    } else {
        // ---- pure fill: x_logits0/1 rows + t_logits0/1 splats ----
        int fb = bid - n_build_blocks;
        unsigned Q = (unsigned)n_rows * D / 4;      // f4 per region (5M)
        f4* r0 = (f4*)(out + n_rows);               // x_logits0
        f4* r1 = r0 + Q;                            // x_logits1
        unsigned stride = (unsigned)n_fill_blocks * 256;
        unsigned q0 = (unsigned)fb * 256 + threadIdx.x;
        for (unsigned q = q0; q < Q; q += stride) {
            int cb = (int)(q % 5u) * 4;             // column base 0,4,8,12,16
            float b0 = dx_b[cb + 0], b1 = dx_b[cb + 1];
            float b2 = dx_b[cb + 2], b3 = dx_b[cb + 3];
            float w0 = dx_w[cb + 0], w1 = dx_w[cb + 1];
            float w2 = dx_w[cb + 2], w3 = dx_w[cb + 3];
            f4 v0 = {b0, b1, b2, b3};
            f4 v1 = {w0 + b0, w1 + b1, w2 + b2, w3 + b3};
            r0[q] = v0;
            r1[q] = v1;
        }
        // constant heads: t_logits0 = tb, t_logits1 = tw + tb
        float tw = *sc_tw, tb = *sc_tb;
        f4 s0 = {tb, tb, tb, tb};
        float t1v = tw + tb;
        f4 s1 = {t1v, t1v, t1v, t1v};
        size_t o3 = (size_t)n_rows * (size_t)(1 + 2 * D);
        unsigned Qt = (unsigned)n_rows / 4;         // 250K f4 per region
        f4* h0 = (f4*)(out + o3);
        f4* h1 = (f4*)(out + o3 + (size_t)n_rows);
        for (unsigned q = q0; q < Qt; q += stride) {
            h0[q] = s0;
            h1[q] = s1;
        }
    }
}

// ---------------------------------------------------------------------------
// Kernel B: rows job alone. Working set ~96 MB streams + 8.4 MB table, all
// < 256 MB L3 -> gathers are L3 hits. One 4B gather, coalesced f4 x loads,
// lane-consecutive stores for z / y_logits0 / y_logits1.
// ---------------------------------------------------------------------------
template <bool USE_TAB>
__global__ __launch_bounds__(256) void cevae_B_rows(
    const float* __restrict__ x, const float* __restrict__ t,
    const float* __restrict__ y, const u32* __restrict__ tab,
    const float* __restrict__ qz_w, const float* __restrict__ qz_b,
    const float* __restrict__ sc_y0w, const float* __restrict__ sc_y0b,
    const float* __restrict__ sc_y1w, const float* __restrict__ sc_y1b,
    const float* __restrict__ pz, float* __restrict__ out, int n_rows)
{
    int n = blockIdx.x * 256 + threadIdx.x;
    if (n >= n_rows) return;

    const f4* xr = (const f4*)(x + (size_t)n * D);
    f4 a = xr[0];
    f4 b = xr[1];
    f4 c = xr[2];
    f4 d = xr[3];
    f4 e = xr[4];
    float tv = t[n];
    float yv = y[n];

    unsigned idx = (tv != 0.0f) ? (1u << 20) : 0u;
    idx |= ((unsigned)a.x) << 19;
    idx |= ((unsigned)a.y) << 18;
    idx |= ((unsigned)a.z) << 17;
    idx |= ((unsigned)a.w) << 16;
    idx |= ((unsigned)b.x) << 15;
    idx |= ((unsigned)b.y) << 14;
    idx |= ((unsigned)b.z) << 13;
    idx |= ((unsigned)b.w) << 12;
    idx |= ((unsigned)c.x) << 11;
    idx |= ((unsigned)c.y) << 10;
    idx |= ((unsigned)c.z) << 9;
    idx |= ((unsigned)c.w) << 8;
    idx |= ((unsigned)d.x) << 7;
    idx |= ((unsigned)d.y) << 6;
    idx |= ((unsigned)d.z) << 5;
    idx |= ((unsigned)d.w) << 4;
    idx |= ((unsigned)e.x) << 3;
    idx |= ((unsigned)e.y) << 2;
    idx |= ((unsigned)e.z) << 1;
    idx |= ((unsigned)e.w);

    float z;
    if (USE_TAB) {
        u32 g = tab[idx];                      // ONE random 4B request, L3-hot
        z = fmaf(__uint_as_float(g & 0xFFFF0000u), yv,
                 __uint_as_float(g << 16));
    } else {
        z = fmaf(qz_w[idx], yv, qz_b[idx]);
    }
    out[n] = z;

    float y0w = *sc_y0w, y0b = *sc_y0b;
    float y1w = *sc_y1w, y1b = *sc_y1b;

    // layout: [z(N)][xl0(N*D)][xl1(N*D)][t0(N)][t1(N)][y0(N)][y1(N)][pz(1)]
    size_t o3 = (size_t)n_rows * (size_t)(1 + 2 * D);
    out[o3 + 2 * (size_t)n_rows + n] = fmaf(tv, y1b - y0b, y0b);
    out[o3 + 3 * (size_t)n_rows + n] = fmaf(tv, (y1w + y1b) - (y0w + y0b), y0w + y0b);
    if (n == 0) out[o3 + 4 * (size_t)n_rows] = pz[0];
}

extern "C" void kernel_launch(void* const* d_in, const int* in_sizes, int n_in,
                              void* d_out, int out_size, void* d_ws, size_t ws_size,
                              hipStream_t stream) {
    const float* x    = (const float*)d_in[0];
    const float* t    = (const float*)d_in[1];
    const float* y    = (const float*)d_in[2];
    const float* qz_w = (const float*)d_in[3];
    const float* qz_b = (const float*)d_in[4];
    const float* dx_w = (const float*)d_in[5];
    const float* dx_b = (const float*)d_in[6];
    const float* t_w  = (const float*)d_in[7];
    const float* t_b  = (const float*)d_in[8];
    const float* y0_w = (const float*)d_in[9];
    const float* y0_b = (const float*)d_in[10];
    const float* y1_w = (const float*)d_in[11];
    const float* y1_b = (const float*)d_in[12];
    const float* pz   = (const float*)d_in[13];
    float* out = (float*)d_out;

    int n_rows = in_sizes[0] / D;            // 1,000,000
    int nc     = in_sizes[3];                // 2^21
    int n_rb = (n_rows + 255) / 256;         // 3907 rows blocks

    size_t tab_bytes = (size_t)nc * sizeof(u32);   // 8.4 MB
    if (ws_size >= tab_bytes) {
        uint4* tab = (uint4*)d_ws;
        int nq = nc / 4;                           // 524,288
        int n_build_blocks = (nq + 255) / 256;     // 2048
        int n_fill_blocks  = 4096;
        cevae_A_build_fill<<<n_build_blocks + n_fill_blocks, 256, 0, stream>>>(
            (const f4*)qz_w, (const f4*)qz_b, tab, nq,
            dx_w, dx_b, t_w, t_b, out, n_rows, n_build_blocks, n_fill_blocks);
        cevae_B_rows<true><<<n_rb, 256, 0, stream>>>(
            x, t, y, (const u32*)tab, qz_w, qz_b,
            y0_w, y0_b, y1_w, y1_b, pz, out, n_rows);
    } else {
        // fallback: no workspace -> fill via A (build part skipped by nq=0),
        // rows read the two float tables directly.
        cevae_A_build_fill<<<4096, 256, 0, stream>>>(
            (const f4*)qz_w, (const f4*)qz_b, nullptr, 0,
            dx_w, dx_b, t_w, t_b, out, n_rows, 0, 4096);
        cevae_B_rows<false><<<n_rb, 256, 0, stream>>>(
            x, t, y, nullptr, qz_w, qz_b,
            y0_w, y0_b, y1_w, y1_b, pz, out, n_rows);
    }
}

// Round 10
// 66.088 us; speedup vs baseline: 1.3675x; 1.0217x over previous
//
#include <hip/hip_runtime.h>

constexpr int D = 20;

typedef float f4 __attribute__((ext_vector_type(4)));
typedef unsigned int u32;

__device__ __forceinline__ u32 bf16_rne(float f) {
    u32 u = __float_as_uint(f);
    return (u + 0x7FFFu + ((u >> 16) & 1u)) >> 16;
}

// ---------------------------------------------------------------------------
// K1: pack (qz_w, qz_b) as bf16 pair into one uint32 per entry (8.4 MB).
// ---------------------------------------------------------------------------
__global__ __launch_bounds__(256) void cevae_build_tab(
    const f4* __restrict__ qw, const f4* __restrict__ qb,
    uint4* __restrict__ tab, int nq)   // nq = nc/4
{
    int i = blockIdx.x * 256 + threadIdx.x;
    if (i >= nq) return;
    f4 w = qw[i];
    f4 b = qb[i];
    uint4 o;
    o.x = (bf16_rne(w.x) << 16) | bf16_rne(b.x);
    o.y = (bf16_rne(w.y) << 16) | bf16_rne(b.y);
    o.z = (bf16_rne(w.z) << 16) | bf16_rne(b.z);
    o.w = (bf16_rne(w.w) << 16) | bf16_rne(b.w);
    tab[i] = o;
}

// ---------------------------------------------------------------------------
// K2: fused rows + fill, roles in groups of 8 consecutive blocks (even XCD
// spread). KEY CHANGE vs round 8: all pure-fill stores are NONTEMPORAL
// (evict-first) so the 168 MB write stream does not sweep the 8.4 MB gather
// table out of L3. Rows-side loads/stores stay cached.
//   rows job: one 4B gather -> z; y_logits0/1; lane-consecutive stores.
//   fill job: flat coalesced nt f4 fill of x_logits0/1 + t_logits0/1.
// ---------------------------------------------------------------------------
template <bool USE_TAB>
__global__ __launch_bounds__(256) void cevae_fused7_kernel(
    const float* __restrict__ x, const float* __restrict__ t,
    const float* __restrict__ y, const u32* __restrict__ tab,
    const float* __restrict__ qz_w, const float* __restrict__ qz_b,
    const float* __restrict__ dx_w, const float* __restrict__ dx_b,
    const float* __restrict__ sc_tw, const float* __restrict__ sc_tb,
    const float* __restrict__ sc_y0w, const float* __restrict__ sc_y0b,
    const float* __restrict__ sc_y1w, const float* __restrict__ sc_y1b,
    const float* __restrict__ pz, float* __restrict__ out, int n_rows,
    int n_job_blocks)
{
    int bid = blockIdx.x;
    int sub = ((bid >> 4) << 3) | (bid & 7);   // block index within its role
    size_t o3 = (size_t)n_rows * (size_t)(1 + 2 * D);

    if (((bid >> 3) & 1) == 0) {
        // ---------------- rows job ----------------
        int n = sub * 256 + threadIdx.x;
        if (n >= n_rows) return;

        const f4* xr = (const f4*)(x + (size_t)n * D);
        f4 a = xr[0];
        f4 b = xr[1];
        f4 c = xr[2];
        f4 d = xr[3];
        f4 e = xr[4];
        float tv = t[n];
        float yv = y[n];

        unsigned idx = (tv != 0.0f) ? (1u << 20) : 0u;
        idx |= ((unsigned)a.x) << 19;
        idx |= ((unsigned)a.y) << 18;
        idx |= ((unsigned)a.z) << 17;
        idx |= ((unsigned)a.w) << 16;
        idx |= ((unsigned)b.x) << 15;
        idx |= ((unsigned)b.y) << 14;
        idx |= ((unsigned)b.z) << 13;
        idx |= ((unsigned)b.w) << 12;
        idx |= ((unsigned)c.x) << 11;
        idx |= ((unsigned)c.y) << 10;
        idx |= ((unsigned)c.z) << 9;
        idx |= ((unsigned)c.w) << 8;
        idx |= ((unsigned)d.x) << 7;
        idx |= ((unsigned)d.y) << 6;
        idx |= ((unsigned)d.z) << 5;
        idx |= ((unsigned)d.w) << 4;
        idx |= ((unsigned)e.x) << 3;
        idx |= ((unsigned)e.y) << 2;
        idx |= ((unsigned)e.z) << 1;
        idx |= ((unsigned)e.w);

        float z;
        if (USE_TAB) {
            u32 g = tab[idx];                  // one random 4B request, L3-hot
            z = fmaf(__uint_as_float(g & 0xFFFF0000u), yv,
                     __uint_as_float(g << 16));
        } else {
            z = fmaf(qz_w[idx], yv, qz_b[idx]);
        }
        out[n] = z;

        float y0w = *sc_y0w, y0b = *sc_y0b;
        float y1w = *sc_y1w, y1b = *sc_y1b;

        // layout: [z(N)][xl0(N*D)][xl1(N*D)][t0(N)][t1(N)][y0(N)][y1(N)][pz(1)]
        out[o3 + 2 * (size_t)n_rows + n] = fmaf(tv, y1b - y0b, y0b);
        out[o3 + 3 * (size_t)n_rows + n] = fmaf(tv, (y1w + y1b) - (y0w + y0b), y0w + y0b);
        if (n == 0) out[o3 + 4 * (size_t)n_rows] = pz[0];
    } else {
        // ---------------- fill job (coalesced flat NT f4 stores) ----------------
        unsigned Q = (unsigned)n_rows * D / 4;      // f4 per region (5M)
        f4* r0 = (f4*)(out + n_rows);               // x_logits0
        f4* r1 = r0 + Q;                            // x_logits1
        unsigned stride = (unsigned)n_job_blocks * 256;
        unsigned q0 = (unsigned)sub * 256 + threadIdx.x;
        for (unsigned q = q0; q < Q; q += stride) {
            int cb = (int)(q % 5u) * 4;             // column base 0,4,8,12,16
            float b0 = dx_b[cb + 0], b1 = dx_b[cb + 1];
            float b2 = dx_b[cb + 2], b3 = dx_b[cb + 3];
            float w0 = dx_w[cb + 0], w1 = dx_w[cb + 1];
            float w2 = dx_w[cb + 2], w3 = dx_w[cb + 3];
            f4 v0 = {b0, b1, b2, b3};
            f4 v1 = {w0 + b0, w1 + b1, w2 + b2, w3 + b3};
            __builtin_nontemporal_store(v0, r0 + q);
            __builtin_nontemporal_store(v1, r1 + q);
        }
        // constant heads: t_logits0 = tb, t_logits1 = tw + tb
        float tw = *sc_tw, tb = *sc_tb;
        f4 s0 = {tb, tb, tb, tb};
        float t1v = tw + tb;
        f4 s1 = {t1v, t1v, t1v, t1v};
        unsigned Qt = (unsigned)n_rows / 4;         // 250K f4 per region
        f4* h0 = (f4*)(out + o3);
        f4* h1 = (f4*)(out + o3 + (size_t)n_rows);
        for (unsigned q = q0; q < Qt; q += stride) {
            __builtin_nontemporal_store(s0, h0 + q);
            __builtin_nontemporal_store(s1, h1 + q);
        }
    }
}

extern "C" void kernel_launch(void* const* d_in, const int* in_sizes, int n_in,
                              void* d_out, int out_size, void* d_ws, size_t ws_size,
                              hipStream_t stream) {
    const float* x    = (const float*)d_in[0];
    const float* t    = (const float*)d_in[1];
    const float* y    = (const float*)d_in[2];
    const float* qz_w = (const float*)d_in[3];
    const float* qz_b = (const float*)d_in[4];
    const float* dx_w = (const float*)d_in[5];
    const float* dx_b = (const float*)d_in[6];
    const float* t_w  = (const float*)d_in[7];
    const float* t_b  = (const float*)d_in[8];
    const float* y0_w = (const float*)d_in[9];
    const float* y0_b = (const float*)d_in[10];
    const float* y1_w = (const float*)d_in[11];
    const float* y1_b = (const float*)d_in[12];
    const float* pz   = (const float*)d_in[13];
    float* out = (float*)d_out;

    int n_rows = in_sizes[0] / D;            // 1,000,000
    int nc     = in_sizes[3];                // 2^21
    int n_rb = (n_rows + 255) / 256;         // 3907 rows blocks needed
    int n_groups = (n_rb + 7) / 8;           // groups of 8 blocks per role
    int n_job_blocks = n_groups * 8;         // blocks per role

    size_t tab_bytes = (size_t)nc * sizeof(u32);   // 8.4 MB
    if (ws_size >= tab_bytes) {
        uint4* tab = (uint4*)d_ws;
        int nq = nc / 4;                     // 524,288
        cevae_build_tab<<<(nq + 255) / 256, 256, 0, stream>>>(
            (const f4*)qz_w, (const f4*)qz_b, tab, nq);
        cevae_fused7_kernel<true><<<n_groups * 16, 256, 0, stream>>>(
            x, t, y, (const u32*)tab, qz_w, qz_b, dx_w, dx_b, t_w, t_b,
            y0_w, y0_b, y1_w, y1_b, pz, out, n_rows, n_job_blocks);
    } else {
        cevae_fused7_kernel<false><<<n_groups * 16, 256, 0, stream>>>(
            x, t, y, nullptr, qz_w, qz_b, dx_w, dx_b, t_w, t_b,
            y0_w, y0_b, y1_w, y1_b, pz, out, n_rows, n_job_blocks);
    }
}